// Round 8
// baseline (429.791 us; speedup 1.0000x reference)
//
#include <hip/hip_runtime.h>
#include <stdint.h>

typedef int v4i __attribute__((ext_vector_type(4)));
typedef int v16i __attribute__((ext_vector_type(16)));

__device__ __forceinline__ int clamp_i8(int v) {
    return v < -128 ? -128 : (v > 127 ? 127 : v);
}

__device__ __forceinline__ void async_load16(const void* g, void* l) {
    __builtin_amdgcn_global_load_lds(
        (const __attribute__((address_space(1))) void*)g,
        (__attribute__((address_space(3))) void*)l, 16, 0, 0);
}

// ---------------- pre-pass 1: quantize fp32 input -> int8 -------------------
__global__ void quant_input_kernel(const float4* __restrict__ x, int* __restrict__ q,
                                   const float* __restrict__ scale_p,
                                   const int* __restrict__ zp_p, int n4) {
    const float inv = 1.0f / *scale_p;
    const int zp = *zp_p;
    const int stride = gridDim.x * blockDim.x;
    for (int t = blockIdx.x * blockDim.x + threadIdx.x; t < n4; t += stride) {
        float4 v = x[t];
        int q0 = clamp_i8((int)rintf(v.x * inv) + zp);
        int q1 = clamp_i8((int)rintf(v.y * inv) + zp);
        int q2 = clamp_i8((int)rintf(v.z * inv) + zp);
        int q3 = clamp_i8((int)rintf(v.w * inv) + zp);
        q[t] = (q0 & 255) | ((q1 & 255) << 8) | ((q2 & 255) << 16) | ((q3 & 255) << 24);
    }
}

// ---------------- pre-pass 2: pack int32 weight -> int8 B-FRAGMENTS ---------
// Fragment-order layout (verified R7, absmax 0): fragment
// t = ((c32 * (K/32) + k32) * 64 + lane), 16 bytes, holding
// col = c32*32 + (lane&31), k = k32*32 + (lane>>5)*16 + 0..15 — the exact
// mfma_i32_32x32x32_i8 B-operand identity. Each lane reads 64B contiguous.
__global__ void pack_weight_kernel(const int* __restrict__ w, int4* __restrict__ q,
                                   int K, int nfrag) {
    const int stride = gridDim.x * blockDim.x;
    const int Kc32 = K / 32;
    for (int t = blockIdx.x * blockDim.x + threadIdx.x; t < nfrag; t += stride) {
        const int l = t & 63;
        const int rest = t >> 6;
        const int k32 = rest % Kc32;
        const int c32 = rest / Kc32;
        const int col = c32 * 32 + (l & 31);
        const int kb = k32 * 32 + (l >> 5) * 16;
        const int* src = w + (int64_t)col * K + kb;
        int4 out;
        int* op = (int*)&out;
#pragma unroll
        for (int j = 0; j < 4; j++) {
            int4 v = *(const int4*)(src + 4 * j);
            op[j] = (v.x & 255) | ((v.y & 255) << 8) | ((v.z & 255) << 16) | ((v.w & 255) << 24);
        }
        q[t] = out;
    }
}

// ---------------- main GEMM: C[i][j] = sum_k A[i][k] * W[j][k] ----------------
// ROUND 8: OCCUPANCY play. Cross-round ledger: R1 (8 waves/CU) has MFMA 149k,
// LDS 244k, wall 377k cy/CU — nothing saturated -> concurrency-starved.
// R5 killed occupancy (1 wave/SIMD, 34%); R2/4/6 reschedule at 2/SIMD (null);
// R7 cut LDS (conflicts -33% confirmed) but exposed bf L2 latency at the
// barrier (174us). This round: block 128x128, 4 waves 2x2, wave tile 64x64
// (acc 64 + af 16 + bf dbuf 32 + addr ~40 -> fits 170) ->
// __launch_bounds__(256,3) = 3 waves/SIMD, 12 waves/CU. B in registers
// (R7 fragment pack) with DOUBLE-BUFFERED bf loaded one tile EARLY, issued
// before the MFMA cluster -> full compute phase to land, drained free by the
// next __syncthreads. A-in-LDS 2x8KB double buffer, R1 barrier loop,
// verified swizzle (all new row offsets === 0 mod 8 -> formulas unchanged).
#define BM 128
#define BN 128
#define BK 64

__global__ __launch_bounds__(256, 3) void gemm_i8_kernel(
    const int8_t* __restrict__ A, const int8_t* __restrict__ W,
    const int* __restrict__ bias, int* __restrict__ C,
    const float* __restrict__ oscale_p, const int* __restrict__ ozp_p,
    int N, int K, int M) {
    __shared__ int8_t lA[2][BM * BK];  // 2 x 8 KiB = 16 KiB total

    const int tid = threadIdx.x;
    const int lane = tid & 63;
    const int w = tid >> 6;   // wave 0..3
    const int wm = w >> 1;    // wave row (0..1), tile rows wm*64
    const int wn = w & 1;     // wave col (0..1), tile cols wn*64

    const int bm = blockIdx.y * BM;
    const int bn = blockIdx.x * BN;

    // --- A staging: 8KB/tile = 2 x 1KB loads per wave; rows w*32 + s_sub (+16).
    // lane l -> LDS row base + (l>>2), physical chunk l&3; source chunk is
    // pre-swizzled (l&3) ^ ((row>>1)&3); w*32 === 0 mod 8 keeps the formula.
    const int s_sub = lane >> 2;                                  // 0..15
    const int s_col = (((lane & 3) ^ ((s_sub >> 1) & 3))) * 16;   // swizzled col
    const int8_t* gA = A + (int64_t)(bm + w * 32 + s_sub) * K + s_col;
    const int64_t rs = (int64_t)16 * K;   // +16 rows per chunk
    int8_t* lA0 = &lA[0][w * 2048];
    int8_t* lA1 = &lA[1][w * 2048];

    // --- B fragment pointer (fragment-order layout, see pack_weight_kernel)
    const int Kc32 = K >> 5;
    const int8_t* pB = W + ((int64_t)(blockIdx.x * (BN / 32) + wn * 2) * Kc32 * 64 +
                            lane) * 16;
    const int64_t nsoff = (int64_t)Kc32 * 1024;  // +1 c32 (32 cols)

    // --- A fragment identities (A: [m=lane&31][k=(lane>>5)*16+j])
    const int m0 = lane & 31;
    const int rsw = (m0 >> 1) & 3;   // row-swizzle term
    const int chi = lane >> 5;       // k-half chunk contribution

    v16i acc[2][2];
#pragma unroll
    for (int i = 0; i < 2; i++)
#pragma unroll
        for (int j = 0; j < 2; j++)
#pragma unroll
            for (int r = 0; r < 16; r++) acc[i][j][r] = 0;

    v4i bfA[2][2], bfB[2][2];  // [k0 half][ns], static ping-pong sets

    // prologue: stage A tile 0 -> buf0; load bf set A for tile 0
    {
        async_load16(gA, lA0);
        async_load16(gA + rs, lA0 + 1024);
        gA += BK;
        bfA[0][0] = *(const v4i*)(pB);
        bfA[1][0] = *(const v4i*)(pB + 1024);
        bfA[0][1] = *(const v4i*)(pB + nsoff);
        bfA[1][1] = *(const v4i*)(pB + nsoff + 1024);
        pB += 2048;
    }

    // BODY(t): barrier (drains A-stage for t and bf_cur, both issued in body
    // t-1); stage A(t+1) into alt buf; af ds_reads; EARLY bf_next loads
    // (full MFMA phase to land); MFMA cluster on bf_cur.
#define BODY(CURBUF, BFC, BFN, HASNEXT)                                        \
    do {                                                                       \
        __syncthreads();                                                       \
        if (HASNEXT) {                                                         \
            int8_t* dA = (CURBUF) ? lA0 : lA1;                                 \
            async_load16(gA, dA);                                              \
            async_load16(gA + rs, dA + 1024);                                  \
            gA += BK;                                                          \
        }                                                                      \
        const int8_t* cA = &lA[CURBUF][0];                                     \
        v4i af[2][2];                                                          \
        _Pragma("unroll") for (int kh = 0; kh < 2; kh++) {                     \
            const int cc = (((kh * 2 + chi)) ^ rsw) << 4;                      \
            _Pragma("unroll") for (int ms = 0; ms < 2; ms++)                   \
                af[ms][kh] = *(const v4i*)&cA[(wm * 64 + ms * 32 + m0) * BK +  \
                                              cc];                             \
        }                                                                      \
        if (HASNEXT) {                                                         \
            BFN[0][0] = *(const v4i*)(pB);                                     \
            BFN[1][0] = *(const v4i*)(pB + 1024);                              \
            BFN[0][1] = *(const v4i*)(pB + nsoff);                             \
            BFN[1][1] = *(const v4i*)(pB + nsoff + 1024);                      \
            pB += 2048;                                                        \
        }                                                                      \
        _Pragma("unroll") for (int kh = 0; kh < 2; kh++)                       \
            _Pragma("unroll") for (int ms = 0; ms < 2; ms++)                   \
                _Pragma("unroll") for (int ns = 0; ns < 2; ns++)               \
                    acc[ms][ns] = __builtin_amdgcn_mfma_i32_32x32x32_i8(       \
                        af[ms][kh], BFC[kh][ns], acc[ms][ns], 0, 0, 0);        \
    } while (0)

    const int NT = K / BK;  // 64 (even) for K=4096
    for (int t2 = 0; t2 < NT; t2 += 2) {
        BODY(0, bfA, bfB, true);              // tile t2   (even -> buf0)
        BODY(1, bfB, bfA, (t2 + 2 < NT));     // tile t2+1 (odd  -> buf1)
    }
#undef BODY

    // --- epilogue: requantize, store int32
    // C/D layout (32x32): col = lane&31, row = (reg&3) + 8*(reg>>2) + 4*(lane>>5)
    const float inv_os = 1.0f / *oscale_p;
    const int ozp = *ozp_p;
    const int rbase = 4 * (lane >> 5);
#pragma unroll
    for (int ns = 0; ns < 2; ns++) {
        const int gn = bn + wn * 64 + ns * 32 + m0;
        const int bv = bias[gn];
#pragma unroll
        for (int ms = 0; ms < 2; ms++) {
            const int gm0 = bm + wm * 64 + ms * 32 + rbase;
            v16i a = acc[ms][ns];
#pragma unroll
            for (int reg = 0; reg < 16; reg++) {
                const int row = (reg & 3) + 8 * (reg >> 2);
                int v = a[reg] + bv;
                int q = (int)rintf((float)v * inv_os) + ozp;
                q = clamp_i8(q);
                C[(int64_t)(gm0 + row) * M + gn] = q;
            }
        }
    }
}

extern "C" void kernel_launch(void* const* d_in, const int* in_sizes, int n_in,
                              void* d_out, int out_size, void* d_ws, size_t ws_size,
                              hipStream_t stream) {
    const float* x = (const float*)d_in[0];
    const int* wgt = (const int*)d_in[1];
    const int* bias = (const int*)d_in[2];
    const float* in_scale = (const float*)d_in[3];
    const int* in_zp = (const int*)d_in[4];
    const float* out_scale = (const float*)d_in[5];
    const int* out_zp = (const int*)d_in[6];

    const int64_t x_elems = (int64_t)in_sizes[0];  // N*K
    const int OUT = in_sizes[2];                   // bias length
    const int K = in_sizes[1] / OUT;               // IN
    const int N = (int)(x_elems / K);

    int8_t* qA = (int8_t*)d_ws;
    int8_t* qW = qA + x_elems;

    {
        int n4 = (int)(x_elems / 4);               // 8.4M float4s
        quant_input_kernel<<<4096, 256, 0, stream>>>(
            (const float4*)x, (int*)qA, in_scale, in_zp, n4);
    }
    {
        int nfrag = (int)(((int64_t)OUT * K) / 16);  // 16B fragments
        pack_weight_kernel<<<2048, 256, 0, stream>>>(
            (const int*)wgt, (int4*)qW, K, nfrag);
    }
    dim3 grid(OUT / BN, N / BM);
    gemm_i8_kernel<<<grid, 256, 0, stream>>>(qA, qW, bias, (int*)d_out,
                                             out_scale, out_zp, N, K, OUT);
}